// Round 1
// 870.270 us; speedup vs baseline: 1.0275x; 1.0275x over previous
//
#include <hip/hip_runtime.h>
#include <math.h>

// Problem: y = LayerNorm( irfft(rfft(x, axis=S, ortho) * w, ortho) + x )
// B=32, S=2048, H=1024, fp32.
// Identities used:
//   x + irfft(rfft(x)*w) = irfft(rfft(x)*(w+1))          (ortho: irfft∘rfft = id)
//   irfft_o(rfft_o(x)*w) = unnorm-IFFT(unnorm-FFT(x)*w)/N (fold 1/N into weight)
// So: h = IFFT_full( FFT(z) spectral-unpack * (w+1)/N ), two h-channels packed
// per complex FFT (two-for-one). DC/Nyquist imag parts dropped (pocketfft c2r).
//
// This round: 256-thread WGs (2 FFTs, 32KB LDS -> 5 blocks/CU), float4 global
// I/O, XCD-sliced block swizzle (each XCD owns a contiguous pg-slice: cache
// lines shared by neighbor WGs stay in one L2, weight slice ~1MB L2-resident),
// and a barrier-free wave-per-row LayerNorm.

#define PI_F 3.14159265358979323846f
#define SW(c) ((c) ^ (((c) >> 4) & 15))   // LDS bank de-conflict swizzle (bijective on [0,2048))

__device__ __forceinline__ float2 cadd(float2 a, float2 b){ return make_float2(a.x+b.x, a.y+b.y); }
__device__ __forceinline__ float2 csub(float2 a, float2 b){ return make_float2(a.x-b.x, a.y-b.y); }
__device__ __forceinline__ float2 cmul(float2 a, float2 b){ return make_float2(a.x*b.x - a.y*b.y, a.x*b.y + a.y*b.x); }

// ---- fused double radix-2 DIF stage (lens L and L/2), natural->bitrev order ----
template<int L>
__device__ __forceinline__ void fwd_stage(float2* A, int j){
  constexpr int half = L >> 1;
  const float ang0 = -PI_F / (float)L;
  #pragma unroll
  for (int r = 0; r < 4; ++r){
    int g    = j + (r << 7);          // 512 groups, 128 workers per FFT
    int blk  = g / half;
    int joff = g - blk * half;
    int i0   = blk * (2 * L) + joff;
    float2 u0 = A[SW(i0)];
    float2 u1 = A[SW(i0 + half)];
    float2 u2 = A[SW(i0 + L)];
    float2 u3 = A[SW(i0 + L + half)];
    float sn, cs; __sincosf(ang0 * (float)joff, &sn, &cs);
    float2 w1 = make_float2(cs, sn);           // e^{-i pi joff / L}
    float2 t0  = cadd(u0, u2);
    float2 d02 = csub(u0, u2);
    float2 t1  = cadd(u1, u3);
    float2 d13 = csub(u1, u3);
    float2 t2  = cmul(d02, w1);
    float2 tm  = cmul(d13, w1);
    float2 t3  = make_float2(tm.y, -tm.x);     // * (-i)
    float2 w2  = cmul(w1, w1);                 // e^{-i 2pi joff / L}
    A[SW(i0)]            = cadd(t0, t1);
    A[SW(i0 + half)]     = cmul(csub(t0, t1), w2);
    A[SW(i0 + L)]        = cadd(t2, t3);
    A[SW(i0 + L + half)] = cmul(csub(t2, t3), w2);
  }
}

// ---- fused double radix-2 DIT stage (lens l and 2l), bitrev->natural, +i twiddles ----
template<int l>
__device__ __forceinline__ void inv_stage(float2* A, int j){
  const float angB = PI_F / (float)(2 * l);
  #pragma unroll
  for (int r = 0; r < 4; ++r){
    int g    = j + (r << 7);
    int blk  = g / l;
    int joff = g - blk * l;
    int base = blk * (4 * l);
    int i0 = base + joff;
    float2 u0 = A[SW(i0)];
    float2 u1 = A[SW(i0 + l)];
    float2 u2 = A[SW(i0 + 2*l)];
    float2 u3 = A[SW(i0 + 3*l)];
    float sn, cs; __sincosf(angB * (float)joff, &sn, &cs);
    float2 wB = make_float2(cs, sn);           // e^{+i pi joff / 2l}
    float2 w  = cmul(wB, wB);                  // e^{+i pi joff / l}
    float2 a1 = cmul(u1, w);
    float2 b0 = cadd(u0, a1), b1 = csub(u0, a1);
    float2 a3 = cmul(u3, w);
    float2 b2 = cadd(u2, a3), b3 = csub(u2, a3);
    float2 t2 = cmul(b2, wB);
    float2 c0 = cadd(b0, t2), c2 = csub(b0, t2);
    float2 iwB = make_float2(-wB.y, wB.x);     // i * wB
    float2 t3 = cmul(b3, iwB);
    float2 c1 = cadd(b1, t3), c3 = csub(b1, t3);
    A[SW(i0)]       = c0;
    A[SW(i0 + l)]   = c1;
    A[SW(i0 + 2*l)] = c2;
    A[SW(i0 + 3*l)] = c3;
  }
}

__device__ __forceinline__ float2 fetchW(const float2* __restrict__ wT,
                                         const float2* __restrict__ cw,
                                         int useT, int h, int k){
  if (useT) return wT[(size_t)h * 1025 + k];
  float2 w = cw[(size_t)k * 1024 + h];
  const float inv = 1.0f / 2048.0f;
  return make_float2((w.x + 1.0f) * inv, w.y * inv);
}

// ---- weight prep: wT[h][k] = (cw[k][h] + 1) / 2048, tiled transpose ----
__global__ void prep_w_kernel(const float2* __restrict__ cw, float2* __restrict__ wT){
  __shared__ float2 tile[32][33];
  int k0 = blockIdx.x * 32, h0 = blockIdx.y * 32;
  int tx = threadIdx.x, ty = threadIdx.y;   // 32 x 8
  #pragma unroll
  for (int r = 0; r < 4; ++r){
    int k = k0 + ty + 8 * r;
    if (k < 1025) tile[ty + 8*r][tx] = cw[(size_t)k * 1024 + (h0 + tx)];
  }
  __syncthreads();
  const float inv = 1.0f / 2048.0f;
  #pragma unroll
  for (int r = 0; r < 4; ++r){
    int h = h0 + ty + 8 * r;
    int k = k0 + tx;
    if (k < 1025){
      float2 w = tile[tx][ty + 8*r];
      wT[(size_t)h * 1025 + k] = make_float2((w.x + 1.0f) * inv, w.y * inv);
    }
  }
}

// ---- main FFT filter kernel: 2 channel-pairs (2 FFTs) per WG, 256 threads ----
// 32KB LDS -> 5 blocks/CU (160KB), 20 waves/CU; barriers span only 4 waves.
__global__ __launch_bounds__(256, 5) void fft_filter_kernel(
    const float4* __restrict__ x4,   // [B,S,H/4] as float4 (quads of h)
    const float2* __restrict__ cw,   // raw weights [1025,1024] float2
    const float2* __restrict__ wT,   // transposed weights [1024][1025] or null
    int useT,
    float4* __restrict__ out4){
  __shared__ float2 lds[2][2048];    // 32 KB
  const int t  = threadIdx.x;
  // XCD-sliced bijective swizzle: assuming xcd = blockIdx.x % 8, XCD x owns
  // pg in [32x, 32x+32) for all batches. The 8 WGs sharing each 128B x-line
  // (8 consecutive pg) are co-XCD and near-simultaneous; each XCD's weight
  // slice is 128 channels ~ 1.05MB -> L2-resident across all 32 batches.
  const int bx  = blockIdx.x;
  const int xcd = bx & 7;
  const int ii  = bx >> 3;               // [0, Bn*32)
  const int b   = ii >> 5;
  const int pg  = (xcd << 5) | (ii & 31);// [0,256): quad of channels 4pg..4pg+3
  const int f   = t >> 7;                // which FFT (0..1)
  const int j   = t & 127;               // worker id within FFT
  float2* A = lds[f];

  // load: one float4 = pairs (2pg, 2pg+1) of row s -> FFT0 gets .xy, FFT1 .zw
  {
    #pragma unroll
    for (int it = 0; it < 8; ++it){
      int s = t + (it << 8);
      float4 v = x4[((size_t)b * 2048 + (size_t)s) * 256 + pg];
      lds[0][SW(s)] = make_float2(v.x, v.y);
      lds[1][SW(s)] = make_float2(v.z, v.w);
    }
  }
  __syncthreads();

  // forward DIF: lens 1024..2 (fused pairs), then len=1
  fwd_stage<1024>(A, j); __syncthreads();
  fwd_stage<256>(A, j);  __syncthreads();
  fwd_stage<64>(A, j);   __syncthreads();
  fwd_stage<16>(A, j);   __syncthreads();
  fwd_stage<4>(A, j);    __syncthreads();
  #pragma unroll
  for (int r = 0; r < 8; ++r){
    int m = j + (r << 7);
    int ia = SW(2*m), ib = SW(2*m + 1);
    float2 u = A[ia], v = A[ib];
    A[ia] = cadd(u, v);
    A[ib] = csub(u, v);
  }
  __syncthreads();

  // spectral step: unpack two real spectra, multiply by (w+1)/N, repack Hermitian
  {
    const int hA = (pg << 2) + (f << 1);   // even channel of this FFT
    if (j == 0){
      // k = 0 at pos 0; k = 1024 (Nyquist) at pos br(1024)=1. Drop imag parts (c2r).
      float2 z0 = A[0];
      float2 wa = fetchW(wT, cw, useT, hA, 0);
      float2 wb = fetchW(wT, cw, useT, hA + 1, 0);
      A[0] = make_float2(z0.x * wa.x, z0.y * wb.x);
      int p1 = SW(1);
      float2 zn = A[p1];
      wa = fetchW(wT, cw, useT, hA, 1024);
      wb = fetchW(wT, cw, useT, hA + 1, 1024);
      A[p1] = make_float2(zn.x * wa.x, zn.y * wb.x);
    }
    #pragma unroll
    for (int r = 0; r < 8; ++r){
      int k = 1 + j + (r << 7);
      if (k < 1024){
        int kr = 2048 - k;
        int p1 = SW((int)(__brev((unsigned)k) >> 21));
        int p2 = SW((int)(__brev((unsigned)kr) >> 21));
        float2 Z1 = A[p1], Z2 = A[p2];
        float2 Xa = make_float2(0.5f*(Z1.x + Z2.x), 0.5f*(Z1.y - Z2.y));
        float2 Xb = make_float2(0.5f*(Z1.y + Z2.y), 0.5f*(Z2.x - Z1.x));
        float2 wa = fetchW(wT, cw, useT, hA, k);
        float2 wb = fetchW(wT, cw, useT, hA + 1, k);
        float2 Ya = cmul(Xa, wa);
        float2 Yb = cmul(Xb, wb);
        A[p1] = make_float2(Ya.x - Yb.y, Ya.y + Yb.x);        // V_k
        A[p2] = make_float2(Ya.x + Yb.y, Yb.x - Ya.y);        // V_{N-k} = conj pack
      }
    }
  }
  __syncthreads();

  // inverse DIT: len=1, then fused lens 2..1024
  #pragma unroll
  for (int r = 0; r < 8; ++r){
    int m = j + (r << 7);
    int ia = SW(2*m), ib = SW(2*m + 1);
    float2 u = A[ia], v = A[ib];
    A[ia] = cadd(u, v);
    A[ib] = csub(u, v);
  }
  __syncthreads();
  inv_stage<2>(A, j);   __syncthreads();
  inv_stage<8>(A, j);   __syncthreads();
  inv_stage<32>(A, j);  __syncthreads();
  inv_stage<128>(A, j); __syncthreads();
  inv_stage<512>(A, j); __syncthreads();

  // store: natural order, channels (4pg..4pg+3) = filtered + residual
  {
    #pragma unroll
    for (int it = 0; it < 8; ++it){
      int s = t + (it << 8);
      float2 a = lds[0][SW(s)], c = lds[1][SW(s)];
      out4[((size_t)b * 2048 + (size_t)s) * 256 + pg] = make_float4(a.x, a.y, c.x, c.y);
    }
  }
}

// ---- LayerNorm over H=1024: one wave per row, barrier-free, LDS-free ----
__global__ __launch_bounds__(256) void ln_kernel(float* __restrict__ io,
                                                 const float* __restrict__ gma,
                                                 const float* __restrict__ bta){
  const int wid  = threadIdx.x >> 6;
  const int lane = threadIdx.x & 63;
  const size_t row = (size_t)blockIdx.x * 4 + (size_t)wid;
  float4* r4 = (float4*)io + row * 256;
  float4 v[4];
  #pragma unroll
  for (int q = 0; q < 4; ++q) v[q] = r4[lane + (q << 6)];
  float s1 = 0.0f, s2 = 0.0f;
  #pragma unroll
  for (int q = 0; q < 4; ++q){
    s1 += v[q].x + v[q].y + v[q].z + v[q].w;
    s2 += v[q].x*v[q].x + v[q].y*v[q].y + v[q].z*v[q].z + v[q].w*v[q].w;
  }
  #pragma unroll
  for (int off = 32; off > 0; off >>= 1){
    s1 += __shfl_xor(s1, off);
    s2 += __shfl_xor(s2, off);
  }
  const float mean = s1 * (1.0f / 1024.0f);
  const float var  = s2 * (1.0f / 1024.0f) - mean * mean;
  const float rstd = rsqrtf(fmaxf(var, 0.0f) + 1e-12f);
  const float4* g4 = (const float4*)gma;
  const float4* b4 = (const float4*)bta;
  #pragma unroll
  for (int q = 0; q < 4; ++q){
    float4 gv = g4[lane + (q << 6)];
    float4 bv = b4[lane + (q << 6)];
    float4 o;
    o.x = (v[q].x - mean) * rstd * gv.x + bv.x;
    o.y = (v[q].y - mean) * rstd * gv.y + bv.y;
    o.z = (v[q].z - mean) * rstd * gv.z + bv.z;
    o.w = (v[q].w - mean) * rstd * gv.w + bv.w;
    r4[lane + (q << 6)] = o;
  }
}

extern "C" void kernel_launch(void* const* d_in, const int* in_sizes, int n_in,
                              void* d_out, int out_size, void* d_ws, size_t ws_size,
                              hipStream_t stream){
  const float4* x4  = (const float4*)d_in[0];
  const float2* cw2 = (const float2*)d_in[1];
  const float*  gma = (const float*)d_in[2];
  const float*  bta = (const float*)d_in[3];
  float4* out4 = (float4*)d_out;
  float*  outf = (float*)d_out;

  const int Bn = in_sizes[0] / (2048 * 1024);   // 32

  const size_t needW = (size_t)1025 * 1024 * sizeof(float2);
  const int useT = (ws_size >= needW) ? 1 : 0;
  float2* wT = (float2*)d_ws;

  if (useT){
    hipLaunchKernelGGL(prep_w_kernel, dim3(33, 32), dim3(32, 8), 0, stream, cw2, wT);
  }
  hipLaunchKernelGGL(fft_filter_kernel, dim3(Bn * 256), dim3(256), 0, stream,
                     x4, cw2, wT, useT, out4);
  hipLaunchKernelGGL(ln_kernel, dim3(Bn * 512), dim3(256), 0, stream,
                     outf, gma, bta);
}